// Round 12
// baseline (36.400 us; speedup 1.0000x reference)
//
#include <hip/hip_runtime.h>
#include <hip/hip_bf16.h>

// Problem constants (B,N,H,O) = (2,512,128,32)
#define NN 512
#define HH 128
#define OO 32

// 2*log2(e): tanh(x) = 1 - 2/(2^(KL*xa)*2^(KL*xb)+1) with x = xa+xb
#define KL 2.8853900817779268f
// (1/sqrt(128)) * log2(e): score scale folded with exp2 conversion
#define SCL 0.1275174172f

__device__ __forceinline__ float vexp2(float x) {
    float r; asm("v_exp_f32 %0, %1" : "=v"(r) : "v"(x)); return r;
}
__device__ __forceinline__ float vrcp(float x) {
    float r; asm("v_rcp_f32 %0, %1" : "=v"(r) : "v"(x)); return r;
}
__device__ __forceinline__ float tanh_fast(float x) {
    float e = vexp2(KL * x);
    return 1.0f - 2.0f * vrcp(e + 1.0f);
}
__device__ __forceinline__ float waveRedSum(float v) {
#pragma unroll
    for (int off = 32; off > 0; off >>= 1) v += __shfl_xor(v, off, 64);
    return v;
}
__device__ __forceinline__ float red8(float v) {   // sum within 8-lane group
    v += __shfl_xor(v, 1, 64); v += __shfl_xor(v, 2, 64); v += __shfl_xor(v, 4, 64);
    return v;
}
// Rotated 16-dot: weights pre-rotated at load; LDS x read at rotated offsets
// so each kq group hits a distinct bank quad (conflict-free).
__device__ __forceinline__ float dot16r(const float4* w, const float* x, int rot) {
    float a = 0;
#pragma unroll
    for (int ii = 0; ii < 4; ii++) {
        int i = (ii + rot) & 3;
        float4 xv = *(const float4*)(x + i * 4);
        a = fmaf(xv.x, w[ii].x, a); a = fmaf(xv.y, w[ii].y, a);
        a = fmaf(xv.z, w[ii].z, a); a = fmaf(xv.w, w[ii].w, a);
    }
    return a;
}
__device__ __forceinline__ unsigned short f2bf(float x) {   // RNE f32->bf16
    unsigned u = __float_as_uint(x);
    u += 0x7fffu + ((u >> 16) & 1u);
    return (unsigned short)(u >> 16);
}
__device__ __forceinline__ float bf_lo(unsigned u) { return __uint_as_float((u & 0xffffu) << 16); }
__device__ __forceinline__ float bf_hi(unsigned u) { return __uint_as_float(u & 0xffff0000u); }

// ---------------------------------------------------------------------------
// K1: producer. 256 blocks x 1024 thr, 4 rows/block.
//   cP[bid][h][4] = Ezi packed ; EzjG[gr][h] bf16 ;
//   vP[bid][o][4] = (z@Wq.T)@Wk * SCL (32-vec per row, packed) ;
//   gdG[32] = Wk.T@bq * SCL  (block 0).
// kT is GONE (algebraic elimination).
// ---------------------------------------------------------------------------
__global__ __launch_bounds__(1024, 4) void prep_kernel(
    const float* __restrict__ z,
    const float* __restrict__ W1, const float* __restrict__ b1,
    const float* __restrict__ Wq, const float* __restrict__ Wk,
    const float* __restrict__ bq,
    float* __restrict__ cP, unsigned short* __restrict__ EzjG,
    float* __restrict__ vP, float* __restrict__ gdG) {
    __shared__ float zrow[4][HH];
    __shared__ float qL[4][HH];          // q_nb (no bias; bias cancels in softmax)
    int t = threadIdx.x, bid = blockIdx.x;
    int r0 = bid * 4;
    int kq = t & 7, h = t >> 3, rot = (kq >> 1) & 3;

    // ---- early-issue weight loads ----
    const float4* WqP = (const float4*)(Wq + (size_t)h * HH) + kq * 4;
    const float4* WiP = (const float4*)(W1 + (size_t)h * 2 * HH) + kq * 4;
    const float4* WjP = (const float4*)(W1 + (size_t)h * 2 * HH + HH) + kq * 4;
    float4 wq[4], wi[4], wj[4];
#pragma unroll
    for (int ii = 0; ii < 4; ii++) {
        wq[ii] = WqP[(ii + rot) & 3];
        wi[ii] = WiP[(ii + rot) & 3];
        wj[ii] = WjP[(ii + rot) & 3];
    }
    float vb1 = b1[h];

    // ---- stage z rows ----
    if (t < 4 * HH) zrow[t >> 7][t & 127] = z[(size_t)r0 * HH + t];
    __syncthreads();

    {   // q_nb -> qL (LDS)
        float a0 = red8(dot16r(wq, &zrow[0][kq * 16], rot));
        float a1 = red8(dot16r(wq, &zrow[1][kq * 16], rot));
        float a2 = red8(dot16r(wq, &zrow[2][kq * 16], rot));
        float a3 = red8(dot16r(wq, &zrow[3][kq * 16], rot));
        if (kq == 0) { qL[0][h] = a0; qL[1][h] = a1; qL[2][h] = a2; qL[3][h] = a3; }
    }
    {   // Ezi -> cP packed [bid][h][4]
        float a0 = red8(dot16r(wi, &zrow[0][kq * 16], rot));
        float a1 = red8(dot16r(wi, &zrow[1][kq * 16], rot));
        float a2 = red8(dot16r(wi, &zrow[2][kq * 16], rot));
        float a3 = red8(dot16r(wi, &zrow[3][kq * 16], rot));
        if (kq == 0) {
            float* cp = cP + (size_t)bid * 512 + h * 4;
            cp[0] = vexp2(KL * (a0 + vb1)); cp[1] = vexp2(KL * (a1 + vb1));
            cp[2] = vexp2(KL * (a2 + vb1)); cp[3] = vexp2(KL * (a3 + vb1));
        }
    }
    {   // Ezj -> bf16
        float a0 = red8(dot16r(wj, &zrow[0][kq * 16], rot));
        float a1 = red8(dot16r(wj, &zrow[1][kq * 16], rot));
        float a2 = red8(dot16r(wj, &zrow[2][kq * 16], rot));
        float a3 = red8(dot16r(wj, &zrow[3][kq * 16], rot));
        if (kq == 0) {
            EzjG[(size_t)(r0 + 0) * HH + h] = f2bf(vexp2(KL * a0));
            EzjG[(size_t)(r0 + 1) * HH + h] = f2bf(vexp2(KL * a1));
            EzjG[(size_t)(r0 + 2) * HH + h] = f2bf(vexp2(KL * a2));
            EzjG[(size_t)(r0 + 3) * HH + h] = f2bf(vexp2(KL * a3));
        }
    }
    __syncthreads();   // qL ready

    // ---- v' = q_nb @ Wk * SCL -> vP packed [bid][o][4] ----
    if (t < 512) {
        int r = t >> 7, g = t & 127, o = g >> 2, aq = g & 3;
        float acc = 0;
        int a0 = aq * 32;
#pragma unroll 8
        for (int a = a0; a < a0 + 32; a++)
            acc = fmaf(qL[r][a], Wk[(size_t)a * OO + o], acc);
        acc += __shfl_xor(acc, 1, 64);
        acc += __shfl_xor(acc, 2, 64);
        if (aq == 0) vP[(size_t)bid * 128 + o * 4 + r] = acc * SCL;
    } else if (bid == 0 && t < 544) {
        // gd' = Wk.T @ bq * SCL  (32 outputs, block 0 only)
        int o = t - 512;
        float acc = 0;
#pragma unroll 8
        for (int a = 0; a < HH; a++)
            acc = fmaf(bq[a], Wk[(size_t)a * OO + o], acc);
        gdG[o] = acc * SCL;
    }
}

// ---------------------------------------------------------------------------
// K2: consumer. 256 blocks x 1024 thr, 4 rows/block (1/CU).
//   A : stage v'/gd'/Ezi (tiny) + REGISTER-PREFETCH own Ezj slice (32 u32)
//   B : scores from s_t (INPUT -> local-L2!): e = exp2(v'[r]·s + gd'·s), mask
//       + per-wave row partial sums (no max pass)
//   D : rcp core entirely from regs/LDS (zero global loads)
//   UL: U = 1 - 2*sum/S ; E: tail GEMVs (rotated, conflict-free)
// Cross-XCD traffic in the critical path: ONLY the prefetched Ezj.
// ---------------------------------------------------------------------------
__global__ __launch_bounds__(1024, 4) void fused_kernel(
    const float* __restrict__ s_t,
    const float* __restrict__ vP, const float* __restrict__ gdG,
    const float* __restrict__ cP, const unsigned short* __restrict__ EzjG,
    const float* __restrict__ W2, const float* __restrict__ b2,
    const float* __restrict__ W3, const float* __restrict__ b3,
    const float* __restrict__ W4, const float* __restrict__ b4,
    float* __restrict__ out) {
    __shared__ float v4T[OO][4];         // 512B  v' packed [o][r]
    __shared__ float gdL[OO];            // 128B
    __shared__ float c4T[HH][4];         // 2KB   Ezi packed [h][r]
    __shared__ float eBuf[4][NN];        // 8KB   unnormalized e [r][j]
    __shared__ float sliceS[16][2];      // per-wave row partial sums
    __shared__ float part[16][4][HH];    // 32KB  D partials
    __shared__ float UL[4][HH];          // 2KB
    __shared__ float aggL[4][HH];        // 2KB
    __shared__ float h1L[4][HH];         // 2KB

    int t = threadIdx.x, bid = blockIdx.x;
    int b = bid >> 7, i0 = (bid & 127) * 4;
    int w = t >> 6, lane = t & 63;

    // ---- A: stage block-local tensors (all tiny) ----
    if (t < 128)       ((float*)v4T)[t] = vP[(size_t)bid * 128 + t];
    else if (t < 160)  gdL[t - 128] = gdG[t - 128];
    else if (t >= 512) ((float*)c4T)[t - 512] = cP[(size_t)bid * 512 + (t - 512)];

    // ---- Ezj register prefetch (cross-XCD; latency hidden under A+B) ----
    unsigned uv[32];
    {
        const unsigned* zbU = (const unsigned*)EzjG + (size_t)b * NN * 64 + lane;
#pragma unroll
        for (int jj = 0; jj < 32; jj++) uv[jj] = zbU[(size_t)(w * 32 + jj) * 64];
    }
    __syncthreads();

    // ---- B: scores from s_t (local L2), 32-dot + d[j], exp2, no max ----
    {
        int j = t & 511, rp = t >> 9, ra = 2 * rp;
        const float4* sp = (const float4*)(s_t + ((size_t)b * NN + j) * OO);
        float d0 = 0, d1 = 0, dd = 0;
#pragma unroll
        for (int c = 0; c < 8; c++) {
            float4 sv = sp[c];
            int o0 = c * 4;
            float2 v0 = *(const float2*)&v4T[o0 + 0][ra];   // broadcast
            float2 v1 = *(const float2*)&v4T[o0 + 1][ra];
            float2 v2 = *(const float2*)&v4T[o0 + 2][ra];
            float2 v3 = *(const float2*)&v4T[o0 + 3][ra];
            d0 = fmaf(sv.x, v0.x, d0); d1 = fmaf(sv.x, v0.y, d1); dd = fmaf(sv.x, gdL[o0 + 0], dd);
            d0 = fmaf(sv.y, v1.x, d0); d1 = fmaf(sv.y, v1.y, d1); dd = fmaf(sv.y, gdL[o0 + 1], dd);
            d0 = fmaf(sv.z, v2.x, d0); d1 = fmaf(sv.z, v2.y, d1); dd = fmaf(sv.z, gdL[o0 + 2], dd);
            d0 = fmaf(sv.w, v3.x, d0); d1 = fmaf(sv.w, v3.y, d1); dd = fmaf(sv.w, gdL[o0 + 3], dd);
        }
        float e0 = vexp2(d0 + dd), e1 = vexp2(d1 + dd);
        if (j == i0 + ra)     e0 = 0.0f;   // diagonal mask
        if (j == i0 + ra + 1) e1 = 0.0f;
        eBuf[ra][j] = e0; eBuf[ra + 1][j] = e1;
        float t0 = waveRedSum(e0), t1 = waveRedSum(e1);
        if (lane == 0) { sliceS[w][0] = t0; sliceS[w][1] = t1; }
    }
    __syncthreads();

    // ---- D: rcp core — Ezj from regs, e via LDS broadcast, no global ----
    {
        int hp = lane * 2, jb = w * 32;
        float4 cA = *(const float4*)c4T[hp];       // Ezi rows 0..3 at h=hp
        float4 cB = *(const float4*)c4T[hp + 1];   // at h=hp+1
        float a0A = 0, a1A = 0, a2A = 0, a3A = 0;
        float a0B = 0, a1B = 0, a2B = 0, a3B = 0;
#pragma unroll
        for (int jj = 0; jj < 32; jj++) {
            int jc = jb + jj;
            float Ex = bf_lo(uv[jj]), Ey = bf_hi(uv[jj]);
            float w0 = eBuf[0][jc], w1 = eBuf[1][jc];   // broadcasts
            float w2 = eBuf[2][jc], w3 = eBuf[3][jc];
            a0A = fmaf(w0, vrcp(fmaf(cA.x, Ex, 1.0f)), a0A);
            a1A = fmaf(w1, vrcp(fmaf(cA.y, Ex, 1.0f)), a1A);
            a2A = fmaf(w2, vrcp(fmaf(cA.z, Ex, 1.0f)), a2A);
            a3A = fmaf(w3, vrcp(fmaf(cA.w, Ex, 1.0f)), a3A);
            a0B = fmaf(w0, vrcp(fmaf(cB.x, Ey, 1.0f)), a0B);
            a1B = fmaf(w1, vrcp(fmaf(cB.y, Ey, 1.0f)), a1B);
            a2B = fmaf(w2, vrcp(fmaf(cB.z, Ey, 1.0f)), a2B);
            a3B = fmaf(w3, vrcp(fmaf(cB.w, Ey, 1.0f)), a3B);
        }
        *(float2*)&part[w][0][hp] = make_float2(a0A, a0B);
        *(float2*)&part[w][1][hp] = make_float2(a1A, a1B);
        *(float2*)&part[w][2][hp] = make_float2(a2A, a2B);
        *(float2*)&part[w][3][hp] = make_float2(a3A, a3B);
    }
    __syncthreads();

    // ---- UL reduce with folded normalization ----
    if (t < 512) {
        int r = t >> 7, h = t & 127;
        float s = 0;
#pragma unroll
        for (int q = 0; q < 16; q++) s += part[q][r][h];
        float S = 0;
        int wb2 = (r >> 1) * 8, col = r & 1;
#pragma unroll
        for (int q = 0; q < 8; q++) S += sliceS[wb2 + q][col];
        UL[r][h] = fmaf(-2.0f * vrcp(S), s, 1.0f);   // U = 1 - 2*sum/S
    }
    __syncthreads();

    // ---- E: tail GEMVs, rotated conflict-free reads ----
    {
        int kq = t & 7, h8 = t >> 3, rot = (kq >> 1) & 3;
        int r0 = bid * 4;
        float4 wv[4];
        {   // agg = U@W2.T + b2
            const float4* Wp = (const float4*)(W2 + (size_t)h8 * HH) + kq * 4;
#pragma unroll
            for (int ii = 0; ii < 4; ii++) wv[ii] = Wp[(ii + rot) & 3];
            float a0 = red8(dot16r(wv, &UL[0][kq * 16], rot));
            float a1 = red8(dot16r(wv, &UL[1][kq * 16], rot));
            float a2 = red8(dot16r(wv, &UL[2][kq * 16], rot));
            float a3 = red8(dot16r(wv, &UL[3][kq * 16], rot));
            if (kq == 0) {
                float vb = b2[h8];
                aggL[0][h8] = a0 + vb; aggL[1][h8] = a1 + vb;
                aggL[2][h8] = a2 + vb; aggL[3][h8] = a3 + vb;
            }
        }
        __syncthreads();
        {   // h1 = tanh(agg@W3.T + b3)
            const float4* Wp = (const float4*)(W3 + (size_t)h8 * HH) + kq * 4;
#pragma unroll
            for (int ii = 0; ii < 4; ii++) wv[ii] = Wp[(ii + rot) & 3];
            float a0 = red8(dot16r(wv, &aggL[0][kq * 16], rot));
            float a1 = red8(dot16r(wv, &aggL[1][kq * 16], rot));
            float a2 = red8(dot16r(wv, &aggL[2][kq * 16], rot));
            float a3 = red8(dot16r(wv, &aggL[3][kq * 16], rot));
            if (kq == 0) {
                float vb = b3[h8];
                h1L[0][h8] = tanh_fast(a0 + vb); h1L[1][h8] = tanh_fast(a1 + vb);
                h1L[2][h8] = tanh_fast(a2 + vb); h1L[3][h8] = tanh_fast(a3 + vb);
            }
        }
        __syncthreads();
        {   // out = h1@W4.T + b4
            const float4* Wp = (const float4*)(W4 + (size_t)h8 * HH) + kq * 4;
#pragma unroll
            for (int ii = 0; ii < 4; ii++) wv[ii] = Wp[(ii + rot) & 3];
            float a0 = red8(dot16r(wv, &h1L[0][kq * 16], rot));
            float a1 = red8(dot16r(wv, &h1L[1][kq * 16], rot));
            float a2 = red8(dot16r(wv, &h1L[2][kq * 16], rot));
            float a3 = red8(dot16r(wv, &h1L[3][kq * 16], rot));
            if (kq == 0) {
                float vb = b4[h8];
                out[(size_t)(r0 + 0) * HH + h8] = a0 + vb;
                out[(size_t)(r0 + 1) * HH + h8] = a1 + vb;
                out[(size_t)(r0 + 2) * HH + h8] = a2 + vb;
                out[(size_t)(r0 + 3) * HH + h8] = a3 + vb;
            }
        }
    }
}

extern "C" void kernel_launch(void* const* d_in, const int* in_sizes, int n_in,
                              void* d_out, int out_size, void* d_ws, size_t ws_size,
                              hipStream_t stream) {
    const float* z   = (const float*)d_in[0];
    const float* s_t = (const float*)d_in[1];
    const float* W1  = (const float*)d_in[2];
    const float* b1  = (const float*)d_in[3];
    const float* W2  = (const float*)d_in[4];
    const float* b2  = (const float*)d_in[5];
    const float* Wq  = (const float*)d_in[6];
    const float* bq  = (const float*)d_in[7];
    const float* Wk  = (const float*)d_in[8];
    const float* bk  = (const float*)d_in[9];   // bk cancels in softmax — unused
    const float* W3  = (const float*)d_in[10];
    const float* b3  = (const float*)d_in[11];
    const float* W4  = (const float*)d_in[12];
    const float* b4  = (const float*)d_in[13];
    float* out = (float*)d_out;
    (void)bk; (void)s_t;

    float* ws = (float*)d_ws;
    float* cP = ws;                                         // 131072 f32 packed Ezi
    float* vP = ws + 131072;                                // 32768 f32 packed v'
    float* gdG = ws + 163840;                               // 32 f32
    unsigned short* Ezj = (unsigned short*)(ws + 163904);   // 131072 bf16 [gr][h]

    hipLaunchKernelGGL(prep_kernel, dim3(256), dim3(1024), 0, stream,
                       z, W1, b1, Wq, Wk, bq, cP, Ezj, vP, gdG);
    hipLaunchKernelGGL(fused_kernel, dim3(256), dim3(1024), 0, stream,
                       (const float*)d_in[1], vP, gdG, cP, Ezj,
                       W2, b2, W3, b3, W4, b4, out);
}